// Round 1
// 1361.210 us; speedup vs baseline: 1.1160x; 1.1160x over previous
//
#include <hip/hip_runtime.h>
#include <hip/hip_bf16.h>

// AFNO spectral block. Round 3: fused GEMM1+GEMM2 (o1 stays in LDS).
// Pipeline: prep_w -> fwd_rows -> fwd_cols(in-place) -> gemm_fused -> inv_cols -> inv_rows
//
// buf1: fp32 float2 spectrum [bc=4096][m=8320], m = v*128+u  (272.6 MB)
// buf2: fp32 f2 buffer for inverse path (272.6 MB); Wpack (1 MB) aliases its tail.
// Wpack: bf16 [2 layers][4 groups][n=256][k=256] (k contiguous; layer2 k sigma-permuted)
//
// k_gemm_fused: 512 threads (8 waves, 2x4), block tile 128m x 256n, K=256.
//   phase 1: A fp32->bf16 staged in LDS (32KB), W1 fragments direct from L2 -> acc
//   phase 2: bias+relu -> bf16 o1 tile [32 kq][128 m] in LDS (64KB, XOR-swizzled)
//   phase 3: gemm2 from o1 LDS, W2 fragments direct from L2 (sync-free K loop)
//   epilogue: cross-wave real/imag pairing via LDS E, *origin, RMW buf1 in place.
// MFMA k-order identical to the previous split kernels => bitwise-identical output.

#define NB    8
#define NC    512
#define NG    4
#define ND    128
#define NH    128
#define NW    128
#define NWF   65
#define NM    (NWF * NH)        // 8320
#define LROW  129               // FFT LDS row stride (float2)
#define INV_N 0.0078125f        // 1/128

typedef unsigned short ushortT;
typedef __bf16 bf16x8 __attribute__((ext_vector_type(8)));
typedef float f32x4 __attribute__((ext_vector_type(4)));

__device__ __forceinline__ ushortT f2b(float f) {
    __hip_bfloat16 h = __float2bfloat16(f);
    return __builtin_bit_cast(ushortT, h);
}

// involution permutation for o1's k ordering (store-side packs 8/4 contiguous k')
__device__ __forceinline__ int sigma(int n) {
    return ((n & 15) << 4) | ((n >> 4) & 7) | ((n & 128) >> 4);
}

// ======================= FFT machinery (unchanged, verified) =================
__device__ __forceinline__ int bitrev7(int x) {
    return (int)(__brev((unsigned)x) >> 25);
}

__device__ __forceinline__ void fft128(float2* d, int nrows, int tid, int T,
                                       const float2* tw, bool inv) {
    for (int s = 0; s < 7; s++) {
        int half = 1 << s;
        int nb = nrows << 6;
        for (int idx = tid; idx < nb; idx += T) {
            int row = idx >> 6;
            int bid = idx & 63;
            int j = bid & (half - 1);
            int g = bid >> s;
            int k = (g << (s + 1)) + j;
            float2 w = tw[j << (6 - s)];
            float wy = inv ? -w.y : w.y;
            float2* base = d + row * LROW;
            float2 xl = base[k];
            float2 xh = base[k + half];
            float tr = w.x * xh.x - wy * xh.y;
            float ti = w.x * xh.y + wy * xh.x;
            base[k]        = make_float2(xl.x + tr, xl.y + ti);
            base[k + half] = make_float2(xl.x - tr, xl.y - ti);
        }
        __syncthreads();
    }
}

__device__ __forceinline__ void init_tw(float2* tw, int tid) {
    if (tid < 64) {
        float s, c;
        sincosf(-3.14159265358979323846f * (float)tid / 64.0f, &s, &c);
        tw[tid] = make_float2(c, s);
    }
    __syncthreads();
}

__global__ __launch_bounds__(256) void k_fwd_rows(const float* __restrict__ x,
                                                  float2* __restrict__ s0) {
    __shared__ float2 tw[64];
    __shared__ float2 d[16 * LROW];
    int tid = threadIdx.x;
    int bc = blockIdx.y;
    int h0 = blockIdx.x * 16;
    init_tw(tw, tid);

    const float* xr = x + (size_t)bc * (NH * NW) + (size_t)h0 * NW;
    for (int i = tid; i < 16 * 128; i += 256) {
        int r = i >> 7, w = i & 127;
        d[r * LROW + bitrev7(w)] = make_float2(xr[i], 0.f);
    }
    __syncthreads();
    fft128(d, 16, tid, 256, tw, false);

    float2* o = s0 + (size_t)bc * NM;
    for (int i = tid; i < 65 * 16; i += 256) {
        int v = i >> 4, r = i & 15;
        float2 val = d[r * LROW + v];
        o[v * 128 + h0 + r] = make_float2(val.x * INV_N, val.y * INV_N);
    }
}

__global__ __launch_bounds__(320) void k_fwd_cols(float2* __restrict__ s) {
    __shared__ float2 tw[64];
    __shared__ float2 d[5 * LROW];
    int tid = threadIdx.x;
    int bc = blockIdx.y;
    int v0 = blockIdx.x * 5;
    init_tw(tw, tid);

    float2* p = s + (size_t)bc * NM + (size_t)v0 * 128;
    for (int i = tid; i < 5 * 128; i += 320) {
        int cl = i >> 7, u = i & 127;
        d[cl * LROW + bitrev7(u)] = p[cl * 128 + u];
    }
    __syncthreads();
    fft128(d, 5, tid, 320, tw, false);
    for (int i = tid; i < 5 * 128; i += 320) {
        int cl = i >> 7, u = i & 127;
        p[cl * 128 + u] = d[cl * LROW + u];
    }
}

__global__ __launch_bounds__(256) void k_inv_cols(const float2* __restrict__ y,
                                                  float2* __restrict__ t0) {
    __shared__ float2 tw[64];
    __shared__ float2 d[13 * LROW];
    int tid = threadIdx.x;
    int bc = blockIdx.y;
    int v0 = blockIdx.x * 13;
    init_tw(tw, tid);

    const float2* p = y + (size_t)bc * NM + (size_t)v0 * 128;
    for (int i = tid; i < 13 * 128; i += 256) {
        int cl = i >> 7, u = i & 127;
        d[cl * LROW + bitrev7(u)] = p[cl * 128 + u];
    }
    __syncthreads();
    fft128(d, 13, tid, 256, tw, true);

    float2* o = t0 + (size_t)bc * NM;
    for (int i = tid; i < 128 * 13; i += 256) {
        int h = i / 13, cl = i - h * 13;
        float2 val = d[cl * LROW + h];
        o[h * NWF + v0 + cl] = make_float2(val.x * INV_N, val.y * INV_N);
    }
}

__global__ __launch_bounds__(256) void k_inv_rows(const float2* __restrict__ t0,
                                                  float* __restrict__ out) {
    __shared__ float2 tw[64];
    __shared__ float2 d[16 * LROW];
    int tid = threadIdx.x;
    int bc = blockIdx.y;
    int h0 = blockIdx.x * 16;
    init_tw(tw, tid);

    const float2* p = t0 + (size_t)bc * NM + (size_t)h0 * NWF;
    for (int i = tid; i < 16 * 65; i += 256) {
        int r = i / 65, v = i - r * 65;
        float2 val = p[i];
        d[r * LROW + bitrev7(v)] = val;
        if (v >= 1 && v < 64)
            d[r * LROW + bitrev7(128 - v)] = make_float2(val.x, -val.y);
    }
    __syncthreads();
    fft128(d, 16, tid, 256, tw, true);

    float* o = out + (size_t)bc * (NH * NW) + (size_t)h0 * NW;
    for (int i = tid; i < 16 * 128; i += 256) {
        int r = i >> 7, w = i & 127;
        o[i] = d[r * LROW + w].x;
    }
}

// ======================= Weight prep (unchanged) =============================
__global__ __launch_bounds__(256) void k_prep_w(const float* __restrict__ w1,
                                                const float* __restrict__ w2,
                                                ushortT* __restrict__ Wp) {
    int idx = blockIdx.x * 256 + threadIdx.x;      // 2*4*256*256
    int k = idx & 255;
    int n = (idx >> 8) & 255;
    int g = (idx >> 16) & 3;
    int l = idx >> 18;
    const float* w = l ? w2 : w1;
    int kk = l ? sigma(k) : k;
    int ki = kk & 127, no = n & 127;
    float val;
    if (kk < 128) {
        val = (n < 128) ? w[((0 * NG + g) * ND + ki) * ND + no]
                        : w[((1 * NG + g) * ND + ki) * ND + no];
    } else {
        val = (n < 128) ? -w[((1 * NG + g) * ND + ki) * ND + no]
                        :  w[((0 * NG + g) * ND + ki) * ND + no];
    }
    Wp[((size_t)(l * NG + g) * 256 + n) * 256 + k] = f2b(val);
}

// ======================= Fused GEMM1 + GEMM2 ================================
// grid (65, 32), block 512 (8 waves 2m x 4n). Wave tile 64m x 64n. K=256.
// LDS: one 64KB region, time-multiplexed:
//   phase 1: Alds  [16 kq][128 m] bf16x8 granules (32 KB)
//   phase 2/3: o1l [32 kq][128 m] granules (64 KB), m XOR-swizzled by (kq>>1)&7
//   epilogue: E    [32 ch][129] float2 (33 KB)
__global__ __launch_bounds__(512, 4) void k_gemm_fused(float2* __restrict__ S,
                                                       const ushortT* __restrict__ Wp,
                                                       const float* __restrict__ B1,
                                                       const float* __restrict__ B2) {
    __shared__ unsigned char smem[65536];
    ushortT* Alds = (ushortT*)smem;
    ushortT* o1l  = (ushortT*)smem;
    float2*  E    = (float2*)smem;

    const int tid = threadIdx.x;
    const int mt = blockIdx.x, bk = blockIdx.y;
    const int g = bk & 3;
    const int m0 = mt * 128;
    const int lane = tid & 63, wid = tid >> 6;
    const int col = lane & 15, quad = lane >> 4;
    const int wm = wid & 1, wn = wid >> 1;          // wn in [0,4)

    float2* Ab = S + (size_t)(bk * ND) * NM + m0;
    const ushortT* Wg1 = Wp + (size_t)g * 65536;
    const ushortT* Wg2 = Wp + (size_t)(NG + g) * 65536;

    f32x4 acc[4][4];
#pragma unroll
    for (int i = 0; i < 4; i++)
#pragma unroll
        for (int j = 0; j < 4; j++) acc[i][j] = f32x4{0.f, 0.f, 0.f, 0.f};

    // ---- phase 1: gemm1. A staged fp32->bf16; W1 fragments straight from L2.
    for (int s = 0; s < 2; s++) {
        const int cs = s * 64;
        __syncthreads();
        {
            const int oct = tid >> 6;               // 0..7
            const int mp = (tid & 63) * 2;          // 0..126
            union { ushortT u[8]; uint4 v; } re0, re1, im0, im1;
#pragma unroll
            for (int j = 0; j < 8; j++) {
                const float4 v = *(const float4*)(Ab + (size_t)(cs + oct * 8 + j) * NM + mp);
                re0.u[j] = f2b(v.x); im0.u[j] = f2b(v.y);
                re1.u[j] = f2b(v.z); im1.u[j] = f2b(v.w);
            }
            *(uint4*)&Alds[(oct * 128 + mp) * 8] = re0.v;
            *(uint4*)&Alds[(oct * 128 + mp + 1) * 8] = re1.v;
            *(uint4*)&Alds[((8 + oct) * 128 + mp) * 8] = im0.v;
            *(uint4*)&Alds[((8 + oct) * 128 + mp + 1) * 8] = im1.v;
        }
        __syncthreads();
#pragma unroll
        for (int h = 0; h < 2; h++) {
            const int kbase = h * 128 + cs;
#pragma unroll
            for (int ksl = 0; ksl < 2; ksl++) {
                bf16x8 a[4];
#pragma unroll
                for (int mi = 0; mi < 4; mi++)
                    a[mi] = *(const bf16x8*)&Alds[((h * 8 + ksl * 4 + quad) * 128
                                                   + wm * 64 + mi * 16 + col) * 8];
#pragma unroll
                for (int ni = 0; ni < 4; ni++) {
                    const int n = wn * 64 + ni * 16 + col;
                    bf16x8 b = *(const bf16x8*)(Wg1 + (size_t)n * 256 + kbase
                                                + (ksl * 4 + quad) * 8);
#pragma unroll
                    for (int mi = 0; mi < 4; mi++)
                        acc[mi][ni] = __builtin_amdgcn_mfma_f32_16x16x32_bf16(
                            a[mi], b, acc[mi][ni], 0, 0, 0);
                }
            }
        }
    }

    // ---- phase 2: bias + relu -> bf16 o1 tile in LDS.
    // k' = sigma(n) = col*16 + (wn>>1)*8 + (wn&1)*4 + ni  => granule kq = col*2+(wn>>1),
    // 4 contiguous k' per thread => uint2 store at pos (wn&1)*4.
    float bR[4];
#pragma unroll
    for (int ni = 0; ni < 4; ni++) {
        const int n = wn * 64 + ni * 16 + col;
        bR[ni] = (n < 128) ? B1[g * ND + n] : B1[512 + g * ND + (n - 128)];
    }
    __syncthreads();                                // all Alds reads done
    {
        const int kq = col * 2 + (wn >> 1);
        const int xo = col & 7;                     // (kq>>1)&7
        const int pos = (wn & 1) * 4;
#pragma unroll
        for (int mi = 0; mi < 4; mi++)
#pragma unroll
            for (int r = 0; r < 4; r++) {
                const int ml = wm * 64 + mi * 16 + quad * 4 + r;
                union { ushortT u[4]; uint2 v; } pk;
#pragma unroll
                for (int ni = 0; ni < 4; ni++)
                    pk.u[ni] = f2b(fmaxf(acc[mi][ni][r] + bR[ni], 0.f));
                *(uint2*)&o1l[(kq * 128 + (ml ^ xo)) * 8 + pos] = pk.v;
            }
    }
    __syncthreads();

    // ---- phase 3: gemm2. A from o1 LDS; W2 fragments straight from L2. Sync-free.
#pragma unroll
    for (int i = 0; i < 4; i++)
#pragma unroll
        for (int j = 0; j < 4; j++) acc[i][j] = f32x4{0.f, 0.f, 0.f, 0.f};

#pragma unroll
    for (int kqs = 0; kqs < 8; kqs++) {
        const int kq = kqs * 4 + quad;
        const int xo = (kq >> 1) & 7;
        bf16x8 a[4];
#pragma unroll
        for (int mi = 0; mi < 4; mi++)
            a[mi] = *(const bf16x8*)&o1l[(kq * 128 + ((wm * 64 + mi * 16 + col) ^ xo)) * 8];
#pragma unroll
        for (int ni = 0; ni < 4; ni++) {
            const int n = wn * 64 + ni * 16 + col;
            bf16x8 b = *(const bf16x8*)(Wg2 + (size_t)n * 256 + (size_t)kq * 8);
#pragma unroll
            for (int mi = 0; mi < 4; mi++)
                acc[mi][ni] = __builtin_amdgcn_mfma_f32_16x16x32_bf16(
                    a[mi], b, acc[mi][ni], 0, 0, 0);
        }
    }

    // ---- epilogue: pair (real, imag) across waves via LDS, *origin, RMW in place.
    const int ri = wn >> 1;                          // 0 = real half, 1 = imag half
#pragma unroll
    for (int p = 0; p < 4; p++) {
        __syncthreads();                             // o1l / previous E reads done
        if ((wn & 1) == (p >> 1)) {
#pragma unroll
            for (int q2 = 0; q2 < 2; q2++) {
                const int nic = (p & 1) * 2 + q2;
                const int ch_l = q2 * 16 + col;
                const int ch = p * 32 + ch_l;
                const float bias = ri ? B2[512 + g * ND + ch] : B2[g * ND + ch];
#pragma unroll
                for (int mi = 0; mi < 4; mi++)
#pragma unroll
                    for (int r = 0; r < 4; r++) {
                        const int ml = wm * 64 + mi * 16 + quad * 4 + r;
                        ((float*)&E[ch_l * 129 + ml])[ri] = acc[mi][nic][r] + bias;
                    }
            }
        }
        __syncthreads();
#pragma unroll
        for (int j = 0; j < 8; j++) {
            const int idx = j * 512 + tid;
            const int ch_l = idx >> 7, ml = idx & 127;
            const float2 v = E[ch_l * 129 + ml];
            float2* Yp = Ab + (size_t)(p * 32 + ch_l) * NM + ml;
            const float2 o = *Yp;
            *Yp = make_float2(v.x * o.x - v.y * o.y, v.x * o.y + v.y * o.x);
        }
    }
}

// ======================= launch =============================================
extern "C" void kernel_launch(void* const* d_in, const int* in_sizes, int n_in,
                              void* d_out, int out_size, void* d_ws, size_t ws_size,
                              hipStream_t stream) {
    (void)in_sizes; (void)n_in; (void)out_size; (void)ws_size;
    const float* x  = (const float*)d_in[0];
    const float* w1 = (const float*)d_in[1];
    const float* w2 = (const float*)d_in[2];
    const float* b1 = (const float*)d_in[3];
    const float* b2 = (const float*)d_in[4];
    float* outp = (float*)d_out;

    float2* buf1 = (float2*)d_ws;                        // 272,629,760 B
    float2* buf2 = buf1 + (size_t)NB * NC * NM;          // 272,629,760 B
    ushortT* Wp  = (ushortT*)((char*)buf2 + (size_t)144 * 1024 * 1024);  // 1 MB

    k_prep_w<<<dim3(2048), 256, 0, stream>>>(w1, w2, Wp);
    k_fwd_rows<<<dim3(8, NB * NC), 256, 0, stream>>>(x, buf1);
    k_fwd_cols<<<dim3(13, NB * NC), 320, 0, stream>>>(buf1);
    k_gemm_fused<<<dim3(NM / 128, NB * NG), 512, 0, stream>>>(buf1, Wp, b1, b2);
    k_inv_cols<<<dim3(5, NB * NC), 256, 0, stream>>>(buf1, buf2);
    k_inv_rows<<<dim3(8, NB * NC), 256, 0, stream>>>(buf2, outp);
}

// Round 3
// 1032.692 us; speedup vs baseline: 1.4710x; 1.3181x over previous
//
#include <hip/hip_runtime.h>
#include <hip/hip_bf16.h>

// AFNO spectral block. Round 5: fused whole-image 2D FFTs (trip-count fix).
// Pipeline: prep_w -> fwd2d -> gemm_fused -> inv2d
//
// buf1: fp32 float2 spectrum [bc=4096][m=8320], m = v*128 + h  (272.6 MB)
// Wpack: bf16 [2 layers][4 groups][n=256][k=256] at buf2+144MB; twg (64 f2) after it.
//
// k_fwd2d / k_inv2d: one block per (b,c) image, 512 threads, 64 KB LDS tile
//   [64 rows][128 cols] float2 with XOR swizzle IDX(r,c)=r*128+(c^(r&15)).
//   Forward: pack x[2h]+i*x[2h+1] -> 64 row FFTs -> Hermitian unpack+transpose
//   (register-staged, in-place) -> 64 col FFTs (u=0,64 packed) -> spectrum.
//   Inverse mirrors it; DC/Nyquist columns Hermitian-symmetrized at load
//   (== reference's .real semantics for the non-Hermitian modified spectrum).
//   Twiddles in a 512B global table (L1-resident) to keep LDS at exactly 64KB.

#define NB    8
#define NC    512
#define NG    4
#define ND    128
#define NH    128
#define NW    128
#define NWF   65
#define NM    (NWF * NH)        // 8320
#define INV_N 0.0078125f        // 1/128

typedef unsigned short ushortT;
typedef __bf16 bf16x8 __attribute__((ext_vector_type(8)));
typedef float f32x4 __attribute__((ext_vector_type(4)));

__device__ __forceinline__ ushortT f2b(float f) {
    __hip_bfloat16 h = __float2bfloat16(f);
    return __builtin_bit_cast(ushortT, h);
}

// involution permutation for o1's k ordering (store-side packs contiguous k')
__device__ __forceinline__ int sigma(int n) {
    return ((n & 15) << 4) | ((n >> 4) & 7) | ((n & 128) >> 4);
}

__device__ __forceinline__ int bitrev7(int x) {
    return (int)(__brev((unsigned)x) >> 25);
}

// LDS tile index: row r in [0,64), col c in [0,128). XOR swizzle makes
// fixed-col/varying-row access (the transpose unpack) bank-conflict-free.
__device__ __forceinline__ int IDX(int r, int c) {
    return (r << 7) + (c ^ (r & 15));
}

// 64 rows x 128-pt DIT FFT over the col index. Input bitrev order, output
// natural. 512 threads, 8 butterflies/thread/stage, read-all-then-write-all
// (butterfly pairs are disjoint per thread within a stage, so no race).
__device__ __forceinline__ void fft64x128(float2* D, const float2* __restrict__ twg,
                                          int tid, bool inv) {
    for (int s = 0; s < 7; s++) {
        const int hf = 1 << s;
        float2 xl[8], xh[8], w8[8];
        int i0[8], i1[8];
#pragma unroll
        for (int t = 0; t < 8; t++) {
            const int idx = t * 512 + tid;
            const int r = idx >> 6;
            const int bid = idx & 63;
            const int j = bid & (hf - 1);
            const int k = ((bid >> s) << (s + 1)) + j;
            w8[t] = twg[j << (6 - s)];
            i0[t] = IDX(r, k);
            i1[t] = IDX(r, k + hf);
            xl[t] = D[i0[t]];
            xh[t] = D[i1[t]];
        }
#pragma unroll
        for (int t = 0; t < 8; t++) {
            const float wy = inv ? -w8[t].y : w8[t].y;
            const float tr = w8[t].x * xh[t].x - wy * xh[t].y;
            const float ti = w8[t].x * xh[t].y + wy * xh[t].x;
            D[i0[t]] = make_float2(xl[t].x + tr, xl[t].y + ti);
            D[i1[t]] = make_float2(xl[t].x - tr, xl[t].y - ti);
        }
        __syncthreads();
    }
}

// ======================= Fused forward 2D rFFT ==============================
__global__ __launch_bounds__(512, 4) void k_fwd2d(const float* __restrict__ x,
                                                  float2* __restrict__ s0,
                                                  const float2* __restrict__ twg) {
    __shared__ float2 D[8192];           // exactly 64 KB
    const int tid = threadIdx.x;
    const int bc = blockIdx.x;

    // load + pack h-row pairs: Z[hp][w] = x[2hp][w] + i x[2hp+1][w], bitrev w.
    const float* xr = x + (size_t)bc * (NH * NW);
#pragma unroll
    for (int t = 0; t < 4; t++) {
        int i = t * 512 + tid;           // 2048 tasks x 8 elements
        int hp = i >> 5;
        int w0 = (i & 31) * 4;
        float4 a = *(const float4*)(xr + (size_t)(2 * hp) * NW + w0);
        float4 b = *(const float4*)(xr + (size_t)(2 * hp + 1) * NW + w0);
        D[IDX(hp, bitrev7(w0 + 0))] = make_float2(a.x, b.x);
        D[IDX(hp, bitrev7(w0 + 1))] = make_float2(a.y, b.y);
        D[IDX(hp, bitrev7(w0 + 2))] = make_float2(a.z, b.z);
        D[IDX(hp, bitrev7(w0 + 3))] = make_float2(a.w, b.w);
    }
    __syncthreads();
    fft64x128(D, twg, tid, false);       // row FFTs (over w)

    // unpack rfft pairs + transpose to [u][h] (h at bitrev positions).
    // task (hp, j): j=0 handles u=0 & u=64 (real), j=1..63 handles u=j.
    float2 ra[8], rb[8];
#pragma unroll
    for (int t = 0; t < 8; t++) {
        int i = t * 512 + tid;
        int hp = i >> 6, j = i & 63;
        ra[t] = D[IDX(hp, j)];
        rb[t] = D[IDX(hp, j ? (128 - j) : 64)];
    }
    __syncthreads();
#pragma unroll
    for (int t = 0; t < 8; t++) {
        int i = t * 512 + tid;
        int hp = i >> 6, j = i & 63;
        int c0 = bitrev7(2 * hp), c1 = bitrev7(2 * hp + 1);
        float2 a = ra[t], b = rb[t];
        if (j == 0) {                    // rows 0/64 are real: pack as one col
            D[IDX(0, c0)] = make_float2(a.x, b.x);
            D[IDX(0, c1)] = make_float2(a.y, b.y);
        } else {
            // Xe = (a+conj b)/2 -> row 2hp; Xo = (a-conj b)/(2i) -> row 2hp+1
            D[IDX(j, c0)] = make_float2(0.5f * (a.x + b.x), 0.5f * (a.y - b.y));
            D[IDX(j, c1)] = make_float2(0.5f * (a.y + b.y), 0.5f * (b.x - a.x));
        }
    }
    __syncthreads();
    fft64x128(D, twg, tid, false);       // column FFTs (over h)

    // write spectrum: v=1..63 direct; v=0 & v=64 unpacked from packed row 0.
    float2* o = s0 + (size_t)bc * NM;
#pragma unroll
    for (int t = 0; t < 16; t++) {
        int i = t * 512 + tid;           // 8192 tasks x 1 element
        int r = i >> 7, k = i & 127;
        if (r) {
            float2 v = D[IDX(r, k)];
            o[r * 128 + k] = make_float2(v.x * INV_N, v.y * INV_N);
        } else {
            float2 ck = D[IDX(0, k)];
            float2 cm = D[IDX(0, (128 - k) & 127)];
            o[k] = make_float2(0.5f * (ck.x + cm.x) * INV_N,
                               0.5f * (ck.y - cm.y) * INV_N);
            o[64 * 128 + k] = make_float2(0.5f * (ck.y + cm.y) * INV_N,
                                          0.5f * (cm.x - ck.x) * INV_N);
        }
    }
}

// ======================= Fused inverse 2D rFFT ==============================
__global__ __launch_bounds__(512, 4) void k_inv2d(const float2* __restrict__ y,
                                                  float* __restrict__ out,
                                                  const float2* __restrict__ twg) {
    __shared__ float2 D[8192];
    const int tid = threadIdx.x;
    const int bc = blockIdx.x;

    // load spectrum, bitrev k. v=0/64 Hermitian-symmetrized (== .real drop of
    // the non-Hermitian DC/Nyquist imag parts) and packed into row 0.
    const float2* Yb = y + (size_t)bc * NM;
#pragma unroll
    for (int t = 0; t < 16; t++) {
        int i = t * 512 + tid;           // 8192 tasks x 1 element
        int r = i >> 7, k = i & 127;
        int c = bitrev7(k);
        if (r) {
            D[IDX(r, c)] = Yb[r * 128 + k];
        } else {
            int m = (128 - k) & 127;
            float2 a = Yb[k],            am = Yb[m];
            float2 b = Yb[64 * 128 + k], bm = Yb[64 * 128 + m];
            float h0x = 0.5f * (a.x + am.x), h0y = 0.5f * (a.y - am.y);
            float h6x = 0.5f * (b.x + bm.x), h6y = 0.5f * (b.y - bm.y);
            D[IDX(0, c)] = make_float2(h0x - h6y, h0y + h6x);   // H(S0)+i*H(S64)
        }
    }
    __syncthreads();
    fft64x128(D, twg, tid, true);        // column iFFTs (k -> h)

    // transpose + Hermitian-extend to Z[hp][u] (u at bitrev positions).
    float2 ra[8], rb[8];
#pragma unroll
    for (int t = 0; t < 8; t++) {
        int i = t * 512 + tid;
        int hp = i >> 6, j = i & 63;
        ra[t] = D[IDX(j, 2 * hp)];
        rb[t] = D[IDX(j, 2 * hp + 1)];
    }
    __syncthreads();
#pragma unroll
    for (int t = 0; t < 8; t++) {
        int i = t * 512 + tid;
        int hp = i >> 6, j = i & 63;
        float2 e = ra[t], f = rb[t];
        if (j == 0) {                    // row 0 held (ReX_h[0], ReX_h[64])
            D[IDX(hp, bitrev7(0))]  = make_float2(e.x, f.x);
            D[IDX(hp, bitrev7(64))] = make_float2(e.y, f.y);
        } else {
            // Z[hp][j] = e + i f ;  Z[hp][128-j] = conj(e) + i conj(f)
            D[IDX(hp, bitrev7(j))]       = make_float2(e.x - f.y, e.y + f.x);
            D[IDX(hp, bitrev7(128 - j))] = make_float2(e.x + f.y, f.x - e.y);
        }
    }
    __syncthreads();
    fft64x128(D, twg, tid, true);        // row iFFTs (u -> w)

    // output: z[hp][w] = x[2hp][w] + i x[2hp+1][w]
    float* ob = out + (size_t)bc * (NH * NW);
#pragma unroll
    for (int t = 0; t < 8; t++) {
        int i = t * 512 + tid;           // 4096 tasks x 4 elements
        int hp = i >> 6, w0 = (i & 63) * 2;
        float2 v0 = D[IDX(hp, w0)];
        float2 v1 = D[IDX(hp, w0 + 1)];
        *(float2*)(ob + (size_t)(2 * hp) * NW + w0) =
            make_float2(v0.x * INV_N, v1.x * INV_N);
        *(float2*)(ob + (size_t)(2 * hp + 1) * NW + w0) =
            make_float2(v0.y * INV_N, v1.y * INV_N);
    }
}

// ======================= Weight prep + twiddle table ========================
__global__ __launch_bounds__(256) void k_prep_w(const float* __restrict__ w1,
                                                const float* __restrict__ w2,
                                                ushortT* __restrict__ Wp,
                                                float2* __restrict__ twg) {
    if (blockIdx.x == 0 && threadIdx.x < 64) {
        float s, c;
        sincosf(-3.14159265358979323846f * (float)threadIdx.x / 64.0f, &s, &c);
        twg[threadIdx.x] = make_float2(c, s);
    }
    int idx = blockIdx.x * 256 + threadIdx.x;      // 2*4*256*256
    int k = idx & 255;
    int n = (idx >> 8) & 255;
    int g = (idx >> 16) & 3;
    int l = idx >> 18;
    const float* w = l ? w2 : w1;
    int kk = l ? sigma(k) : k;
    int ki = kk & 127, no = n & 127;
    float val;
    if (kk < 128) {
        val = (n < 128) ? w[((0 * NG + g) * ND + ki) * ND + no]
                        : w[((1 * NG + g) * ND + ki) * ND + no];
    } else {
        val = (n < 128) ? -w[((1 * NG + g) * ND + ki) * ND + no]
                        :  w[((0 * NG + g) * ND + ki) * ND + no];
    }
    Wp[((size_t)(l * NG + g) * 256 + n) * 256 + k] = f2b(val);
}

// ======================= Fused GEMM1 + GEMM2 (unchanged) ====================
__global__ __launch_bounds__(512, 4) void k_gemm_fused(float2* __restrict__ S,
                                                       const ushortT* __restrict__ Wp,
                                                       const float* __restrict__ B1,
                                                       const float* __restrict__ B2) {
    __shared__ unsigned char smem[65536];
    ushortT* Alds = (ushortT*)smem;
    ushortT* o1l  = (ushortT*)smem;
    float2*  E    = (float2*)smem;

    const int tid = threadIdx.x;
    const int mt = blockIdx.x, bk = blockIdx.y;
    const int g = bk & 3;
    const int m0 = mt * 128;
    const int lane = tid & 63, wid = tid >> 6;
    const int col = lane & 15, quad = lane >> 4;
    const int wm = wid & 1, wn = wid >> 1;          // wn in [0,4)

    float2* Ab = S + (size_t)(bk * ND) * NM + m0;
    const ushortT* Wg1 = Wp + (size_t)g * 65536;
    const ushortT* Wg2 = Wp + (size_t)(NG + g) * 65536;

    f32x4 acc[4][4];
#pragma unroll
    for (int i = 0; i < 4; i++)
#pragma unroll
        for (int j = 0; j < 4; j++) acc[i][j] = f32x4{0.f, 0.f, 0.f, 0.f};

    // ---- phase 1: gemm1. A staged fp32->bf16; W1 fragments straight from L2.
    for (int s = 0; s < 2; s++) {
        const int cs = s * 64;
        __syncthreads();
        {
            const int oct = tid >> 6;               // 0..7
            const int mp = (tid & 63) * 2;          // 0..126
            union { ushortT u[8]; uint4 v; } re0, re1, im0, im1;
#pragma unroll
            for (int j = 0; j < 8; j++) {
                const float4 v = *(const float4*)(Ab + (size_t)(cs + oct * 8 + j) * NM + mp);
                re0.u[j] = f2b(v.x); im0.u[j] = f2b(v.y);
                re1.u[j] = f2b(v.z); im1.u[j] = f2b(v.w);
            }
            *(uint4*)&Alds[(oct * 128 + mp) * 8] = re0.v;
            *(uint4*)&Alds[(oct * 128 + mp + 1) * 8] = re1.v;
            *(uint4*)&Alds[((8 + oct) * 128 + mp) * 8] = im0.v;
            *(uint4*)&Alds[((8 + oct) * 128 + mp + 1) * 8] = im1.v;
        }
        __syncthreads();
#pragma unroll
        for (int h = 0; h < 2; h++) {
            const int kbase = h * 128 + cs;
#pragma unroll
            for (int ksl = 0; ksl < 2; ksl++) {
                bf16x8 a[4];
#pragma unroll
                for (int mi = 0; mi < 4; mi++)
                    a[mi] = *(const bf16x8*)&Alds[((h * 8 + ksl * 4 + quad) * 128
                                                   + wm * 64 + mi * 16 + col) * 8];
#pragma unroll
                for (int ni = 0; ni < 4; ni++) {
                    const int n = wn * 64 + ni * 16 + col;
                    bf16x8 b = *(const bf16x8*)(Wg1 + (size_t)n * 256 + kbase
                                                + (ksl * 4 + quad) * 8);
#pragma unroll
                    for (int mi = 0; mi < 4; mi++)
                        acc[mi][ni] = __builtin_amdgcn_mfma_f32_16x16x32_bf16(
                            a[mi], b, acc[mi][ni], 0, 0, 0);
                }
            }
        }
    }

    // ---- phase 2: bias + relu -> bf16 o1 tile in LDS.
    float bR[4];
#pragma unroll
    for (int ni = 0; ni < 4; ni++) {
        const int n = wn * 64 + ni * 16 + col;
        bR[ni] = (n < 128) ? B1[g * ND + n] : B1[512 + g * ND + (n - 128)];
    }
    __syncthreads();                                // all Alds reads done
    {
        const int kq = col * 2 + (wn >> 1);
        const int xo = col & 7;                     // (kq>>1)&7
        const int pos = (wn & 1) * 4;
#pragma unroll
        for (int mi = 0; mi < 4; mi++)
#pragma unroll
            for (int r = 0; r < 4; r++) {
                const int ml = wm * 64 + mi * 16 + quad * 4 + r;
                union { ushortT u[4]; uint2 v; } pk;
#pragma unroll
                for (int ni = 0; ni < 4; ni++)
                    pk.u[ni] = f2b(fmaxf(acc[mi][ni][r] + bR[ni], 0.f));
                *(uint2*)&o1l[(kq * 128 + (ml ^ xo)) * 8 + pos] = pk.v;
            }
    }
    __syncthreads();

    // ---- phase 3: gemm2. A from o1 LDS; W2 fragments straight from L2.
#pragma unroll
    for (int i = 0; i < 4; i++)
#pragma unroll
        for (int j = 0; j < 4; j++) acc[i][j] = f32x4{0.f, 0.f, 0.f, 0.f};

#pragma unroll
    for (int kqs = 0; kqs < 8; kqs++) {
        const int kq = kqs * 4 + quad;
        const int xo = (kq >> 1) & 7;
        bf16x8 a[4];
#pragma unroll
        for (int mi = 0; mi < 4; mi++)
            a[mi] = *(const bf16x8*)&o1l[(kq * 128 + ((wm * 64 + mi * 16 + col) ^ xo)) * 8];
#pragma unroll
        for (int ni = 0; ni < 4; ni++) {
            const int n = wn * 64 + ni * 16 + col;
            bf16x8 b = *(const bf16x8*)(Wg2 + (size_t)n * 256 + (size_t)kq * 8);
#pragma unroll
            for (int mi = 0; mi < 4; mi++)
                acc[mi][ni] = __builtin_amdgcn_mfma_f32_16x16x32_bf16(
                    a[mi], b, acc[mi][ni], 0, 0, 0);
        }
    }

    // ---- epilogue: pair (real, imag) across waves via LDS, *origin, RMW.
    const int ri = wn >> 1;                          // 0 = real half, 1 = imag
#pragma unroll
    for (int p = 0; p < 4; p++) {
        __syncthreads();
        if ((wn & 1) == (p >> 1)) {
#pragma unroll
            for (int q2 = 0; q2 < 2; q2++) {
                const int nic = (p & 1) * 2 + q2;
                const int ch_l = q2 * 16 + col;
                const int ch = p * 32 + ch_l;
                const float bias = ri ? B2[512 + g * ND + ch] : B2[g * ND + ch];
#pragma unroll
                for (int mi = 0; mi < 4; mi++)
#pragma unroll
                    for (int r = 0; r < 4; r++) {
                        const int ml = wm * 64 + mi * 16 + quad * 4 + r;
                        ((float*)&E[ch_l * 129 + ml])[ri] = acc[mi][nic][r] + bias;
                    }
            }
        }
        __syncthreads();
#pragma unroll
        for (int j = 0; j < 8; j++) {
            const int idx = j * 512 + tid;
            const int ch_l = idx >> 7, ml = idx & 127;
            const float2 v = E[ch_l * 129 + ml];
            float2* Yp = Ab + (size_t)(p * 32 + ch_l) * NM + ml;
            const float2 o = *Yp;
            *Yp = make_float2(v.x * o.x - v.y * o.y, v.x * o.y + v.y * o.x);
        }
    }
}

// ======================= launch =============================================
extern "C" void kernel_launch(void* const* d_in, const int* in_sizes, int n_in,
                              void* d_out, int out_size, void* d_ws, size_t ws_size,
                              hipStream_t stream) {
    (void)in_sizes; (void)n_in; (void)out_size; (void)ws_size;
    const float* x  = (const float*)d_in[0];
    const float* w1 = (const float*)d_in[1];
    const float* w2 = (const float*)d_in[2];
    const float* b1 = (const float*)d_in[3];
    const float* b2 = (const float*)d_in[4];
    float* outp = (float*)d_out;

    float2* buf1 = (float2*)d_ws;                        // 272,629,760 B
    char*   ws2  = (char*)d_ws + (size_t)NB * NC * NM * sizeof(float2);
    ushortT* Wp  = (ushortT*)(ws2 + (size_t)144 * 1024 * 1024);   // 1 MB
    float2* twg  = (float2*)((char*)Wp + (size_t)1048576);        // 512 B

    k_prep_w<<<dim3(2048), 256, 0, stream>>>(w1, w2, Wp, twg);
    k_fwd2d<<<dim3(NB * NC), 512, 0, stream>>>(x, buf1, twg);
    k_gemm_fused<<<dim3(NM / 128, NB * NG), 512, 0, stream>>>(buf1, Wp, b1, b2);
    k_inv2d<<<dim3(NB * NC), 512, 0, stream>>>(buf1, outp, twg);
}